// Round 6
// baseline (264.094 us; speedup 1.0000x reference)
//
#include <hip/hip_runtime.h>
#include <hip/hip_bf16.h>

#define N_NODES 50000
#define N_EDGES 800000
#define DD 64
#define NGRAPH 64

// R1/R3: 51.2M f32 device atomics = 682us (op-rate-bound) -> CSR+gather (263us).
// R5: all kernels <=113us (none beat the 115us harness poison fills in top-5);
// 259us total => agg ~100 (1-deep gather), mlp ~25 (3 waves/SIMD), hist/fill ~35,
// gaps ~50. R6: agg unroll x2 (8x256B in flight/wave), mlp 8-wave, int4 hist/fill.
//
// ws layout: agg[50000*64] f32 | offs[50000] i32 | eids[800000] i32  (~15.5 MB)

__device__ __forceinline__ float swish_f(float v) {
    return v / (1.0f + __expf(-v));
}

__global__ __launch_bounds__(256) void zero_kernel(int4* __restrict__ p, int n4)
{
    const int i = blockIdx.x * 256 + threadIdx.x;
    if (i < n4) p[i] = make_int4(0, 0, 0, 0);
}

// 4 edges per thread via int4 (N_EDGES % 4 == 0)
__global__ __launch_bounds__(256) void hist_kernel(
    const int* __restrict__ col, int* __restrict__ cnt)
{
    const int i = blockIdx.x * 256 + threadIdx.x;
    if (i < N_EDGES / 4) {
        const int4 c = reinterpret_cast<const int4*>(col)[i];
        atomicAdd(&cnt[c.x], 1);
        atomicAdd(&cnt[c.y], 1);
        atomicAdd(&cnt[c.z], 1);
        atomicAdd(&cnt[c.w], 1);
    }
}

// in-place counts -> exclusive starts. single block, 1024 threads, chunked.
__global__ __launch_bounds__(1024) void scan_kernel(int* __restrict__ offs)
{
    const int T = 1024;
    const int C = (N_NODES + T - 1) / T;   // 49
    const int t = threadIdx.x;
    const int base = t * C;

    int s = 0;
    for (int i = 0; i < C; ++i) {
        const int idx = base + i;
        if (idx < N_NODES) s += offs[idx];
    }
    __shared__ int sm[T];
    sm[t] = s;
    __syncthreads();
    for (int d = 1; d < T; d <<= 1) {
        const int v = (t >= d) ? sm[t - d] : 0;
        __syncthreads();
        sm[t] += v;
        __syncthreads();
    }
    int run = (t == 0) ? 0 : sm[t - 1];
    for (int i = 0; i < C; ++i) {
        const int idx = base + i;
        if (idx < N_NODES) {
            const int c = offs[idx];
            offs[idx] = run;
            run += c;
        }
    }
}

// offs[n] = start(n) on entry; on exit offs[n] = start(n+1).
// 4 edges per thread via int4.
__global__ __launch_bounds__(256) void fill_kernel(
    const int* __restrict__ col, int* __restrict__ offs, int* __restrict__ eids)
{
    const int i = blockIdx.x * 256 + threadIdx.x;
    if (i < N_EDGES / 4) {
        const int4 c = reinterpret_cast<const int4*>(col)[i];
        const int e = i * 4;
        eids[atomicAdd(&offs[c.x], 1)] = e + 0;
        eids[atomicAdd(&offs[c.y], 1)] = e + 1;
        eids[atomicAdd(&offs[c.z], 1)] = e + 2;
        eids[atomicAdd(&offs[c.w], 1)] = e + 3;
    }
}

// one wave per node: 16 dim-lanes x float4; 4 edge slots; unrolled x2 so each
// slot-lane keeps 2x256B in flight (R5 theory: 1-deep chain capped gather BW).
__global__ __launch_bounds__(256) void agg_kernel(
    const float* __restrict__ edge_attr,
    const int* __restrict__ offs,
    const int* __restrict__ eids,
    float* __restrict__ agg)
{
    const int n = (blockIdx.x * 256 + threadIdx.x) >> 6;
    if (n >= N_NODES) return;
    const int lane = threadIdx.x & 63;
    const int q4 = (lane & 15) << 2;  // dim offset
    const int slot = lane >> 4;       // edge slot 0..3
    const int beg = (n == 0) ? 0 : offs[n - 1];
    const int deg = offs[n] - beg;

    float4 acc = make_float4(0.f, 0.f, 0.f, 0.f);
    int i = slot;
    for (; i + 4 < deg; i += 8) {
        const int e0 = eids[beg + i];
        const int e1 = eids[beg + i + 4];
        const float4 v0 = *reinterpret_cast<const float4*>(edge_attr + (size_t)e0 * DD + q4);
        const float4 v1 = *reinterpret_cast<const float4*>(edge_attr + (size_t)e1 * DD + q4);
        acc.x += v0.x; acc.y += v0.y; acc.z += v0.z; acc.w += v0.w;
        acc.x += v1.x; acc.y += v1.y; acc.z += v1.z; acc.w += v1.w;
    }
    if (i < deg) {
        const int e0 = eids[beg + i];
        const float4 v0 = *reinterpret_cast<const float4*>(edge_attr + (size_t)e0 * DD + q4);
        acc.x += v0.x; acc.y += v0.y; acc.z += v0.z; acc.w += v0.w;
    }
    #pragma unroll
    for (int m = 16; m < 64; m <<= 1) {
        acc.x += __shfl_xor(acc.x, m, 64);
        acc.y += __shfl_xor(acc.y, m, 64);
        acc.z += __shfl_xor(acc.z, m, 64);
        acc.w += __shfl_xor(acc.w, m, 64);
    }
    if (slot == 0)
        *reinterpret_cast<float4*>(agg + (size_t)n * DD + q4) = acc;
}

// ---------------- fused 2-layer MLP: 8 waves x 8 output dims ----------------
__global__ __launch_bounds__(512) void mlp_kernel(
    const float* __restrict__ x,
    const float* __restrict__ agg,
    const float* __restrict__ u,
    const int* __restrict__ batch,
    const float* __restrict__ W1,
    const float* __restrict__ b1,
    const float* __restrict__ W2,
    const float* __restrict__ b2,
    float* __restrict__ out)
{
    __shared__ float sh[64][65];   // (lane*65+k)%32 = (lane+k)%32 -> 2-way, free
    const int lane = threadIdx.x & 63;
    const int j0 = __builtin_amdgcn_readfirstlane((threadIdx.x >> 6) << 3);
    const int node = blockIdx.x * 64 + lane;
    const bool valid = node < N_NODES;
    const int nc = valid ? node : (N_NODES - 1);

    float acc[8];
    #pragma unroll
    for (int j = 0; j < 8; ++j) acc[j] = b1[j0 + j];

    const float* __restrict__ row0 = x + (size_t)nc * DD;
    const float* __restrict__ row1 = agg + (size_t)nc * DD;
    const float* __restrict__ row2 = u + (size_t)batch[nc] * DD;

    #pragma unroll
    for (int s = 0; s < 3; ++s) {
        const float* __restrict__ row = (s == 0) ? row0 : (s == 1) ? row1 : row2;
        const float* __restrict__ w = W1 + (size_t)s * 64 * 64 + j0;
        for (int kk = 0; kk < 64; kk += 4) {
            const float4 v = *reinterpret_cast<const float4*>(row + kk);
            #pragma unroll
            for (int i = 0; i < 4; ++i) {
                const float iv = (i == 0) ? v.x : (i == 1) ? v.y : (i == 2) ? v.z : v.w;
                const float* __restrict__ wr = w + (size_t)(kk + i) * 64;
                #pragma unroll
                for (int j = 0; j < 8; ++j)
                    acc[j] += iv * wr[j];
            }
        }
    }

    #pragma unroll
    for (int j = 0; j < 8; ++j)
        sh[lane][j0 + j] = swish_f(acc[j]);

    __syncthreads();

    float acc2[8];
    #pragma unroll
    for (int j = 0; j < 8; ++j) acc2[j] = b2[j0 + j];
    for (int k = 0; k < 64; ++k) {
        const float hk = sh[lane][k];
        const float* __restrict__ wr = W2 + (size_t)k * 64 + j0;
        #pragma unroll
        for (int j = 0; j < 8; ++j)
            acc2[j] += hk * wr[j];
    }

    if (valid) {
        float* o = out + (size_t)node * DD + j0;
        #pragma unroll
        for (int j = 0; j < 8; j += 4) {
            float4 r;
            r.x = swish_f(acc2[j + 0]);
            r.y = swish_f(acc2[j + 1]);
            r.z = swish_f(acc2[j + 2]);
            r.w = swish_f(acc2[j + 3]);
            *reinterpret_cast<float4*>(o + j) = r;
        }
    }
}

extern "C" void kernel_launch(void* const* d_in, const int* in_sizes, int n_in,
                              void* d_out, int out_size, void* d_ws, size_t ws_size,
                              hipStream_t stream) {
    const float* x         = (const float*)d_in[0];
    const int*   ei        = (const int*)d_in[1];
    const float* edge_attr = (const float*)d_in[2];
    const float* u         = (const float*)d_in[3];
    const int*   batch     = (const int*)d_in[4];
    const float* W1        = (const float*)d_in[5];
    const float* b1        = (const float*)d_in[6];
    const float* W2        = (const float*)d_in[7];
    const float* b2        = (const float*)d_in[8];
    float* out = (float*)d_out;

    float* agg = (float*)d_ws;
    int* offs  = (int*)((char*)d_ws + (size_t)N_NODES * DD * sizeof(float));
    int* eids  = offs + N_NODES;
    const int* col = ei + N_EDGES;   // edge_index[1]

    zero_kernel<<<(12500 + 255) / 256, 256, 0, stream>>>((int4*)offs, 12500);
    hist_kernel<<<(N_EDGES / 4 + 255) / 256, 256, 0, stream>>>(col, offs);
    scan_kernel<<<1, 1024, 0, stream>>>(offs);
    fill_kernel<<<(N_EDGES / 4 + 255) / 256, 256, 0, stream>>>(col, offs, eids);
    agg_kernel<<<(N_NODES + 3) / 4, 256, 0, stream>>>(edge_attr, offs, eids, agg);
    mlp_kernel<<<(N_NODES + 63) / 64, 512, 0, stream>>>(x, agg, u, batch, W1, b1, W2, b2, out);
}

// Round 7
// 182.999 us; speedup vs baseline: 1.4431x; 1.4431x over previous
//
#include <hip/hip_runtime.h>
#include <hip/hip_bf16.h>

#define N_NODES 50000
#define N_EDGES 800000
#define DD 64
#define NGRAPH 64
#define SCAN_BLOCKS ((N_NODES + 255) / 256)   // 196

// R1/R3: 51.2M f32 device atomics = 682us (op-rate-bound) -> CSR+gather.
// R5/R6: micro-opts flat at ~260us; rocprof dispatch durations inflated
// (serialized passes) -> model: agg ~100us (latency-bound gather chain),
// scan ~45us (single-block, uncoalesced). R7: hierarchical coalesced scan
// (3 tiny kernels) + agg unroll x4 (16 edge-rows in flight per wave).
//
// ws layout: agg[50000*64] f32 | offs[50000] i32 | eids[800000] i32 | bsum[256]

__device__ __forceinline__ float swish_f(float v) {
    return v / (1.0f + __expf(-v));
}

__global__ __launch_bounds__(256) void zero_kernel(int4* __restrict__ p, int n4)
{
    const int i = blockIdx.x * 256 + threadIdx.x;
    if (i < n4) p[i] = make_int4(0, 0, 0, 0);
}

// 4 edges per thread via int4 (N_EDGES % 4 == 0)
__global__ __launch_bounds__(256) void hist_kernel(
    const int* __restrict__ col, int* __restrict__ cnt)
{
    const int i = blockIdx.x * 256 + threadIdx.x;
    if (i < N_EDGES / 4) {
        const int4 c = reinterpret_cast<const int4*>(col)[i];
        atomicAdd(&cnt[c.x], 1);
        atomicAdd(&cnt[c.y], 1);
        atomicAdd(&cnt[c.z], 1);
        atomicAdd(&cnt[c.w], 1);
    }
}

// ---- hierarchical exclusive scan over offs[N_NODES], coalesced ----
// A: per-block inclusive scan -> offs[idx] = exclusive-within-block; bsum[b]=total
__global__ __launch_bounds__(256) void scanA_kernel(
    int* __restrict__ offs, int* __restrict__ bsum)
{
    __shared__ int sm[256];
    const int t = threadIdx.x;
    const int idx = blockIdx.x * 256 + t;
    const int v = (idx < N_NODES) ? offs[idx] : 0;
    sm[t] = v;
    __syncthreads();
    #pragma unroll
    for (int d = 1; d < 256; d <<= 1) {
        const int w = (t >= d) ? sm[t - d] : 0;
        __syncthreads();
        sm[t] += w;
        __syncthreads();
    }
    if (idx < N_NODES) offs[idx] = sm[t] - v;        // exclusive within block
    if (t == 255) bsum[blockIdx.x] = sm[255];        // block total
}

// B: one block scans the block totals -> bsum[b] = exclusive prefix of blocks
__global__ __launch_bounds__(256) void scanB_kernel(int* __restrict__ bsum)
{
    __shared__ int sm[256];
    const int t = threadIdx.x;
    const int v = (t < SCAN_BLOCKS) ? bsum[t] : 0;
    sm[t] = v;
    __syncthreads();
    #pragma unroll
    for (int d = 1; d < 256; d <<= 1) {
        const int w = (t >= d) ? sm[t - d] : 0;
        __syncthreads();
        sm[t] += w;
        __syncthreads();
    }
    if (t < SCAN_BLOCKS) bsum[t] = sm[t] - v;        // exclusive
}

// C: add block prefix -> offs[n] = global exclusive start(n)
__global__ __launch_bounds__(256) void scanC_kernel(
    int* __restrict__ offs, const int* __restrict__ bsum)
{
    const int idx = blockIdx.x * 256 + threadIdx.x;
    if (idx < N_NODES) offs[idx] += bsum[blockIdx.x];
}

// offs[n] = start(n) on entry; on exit offs[n] = start(n+1) (mutated by atomics).
__global__ __launch_bounds__(256) void fill_kernel(
    const int* __restrict__ col, int* __restrict__ offs, int* __restrict__ eids)
{
    const int i = blockIdx.x * 256 + threadIdx.x;
    if (i < N_EDGES / 4) {
        const int4 c = reinterpret_cast<const int4*>(col)[i];
        const int e = i * 4;
        eids[atomicAdd(&offs[c.x], 1)] = e + 0;
        eids[atomicAdd(&offs[c.y], 1)] = e + 1;
        eids[atomicAdd(&offs[c.z], 1)] = e + 2;
        eids[atomicAdd(&offs[c.w], 1)] = e + 3;
    }
}

// one wave per node: 16 dim-lanes x float4; 4 edge slots; unroll x4 so each
// slot-lane keeps 4 independent eid+attr loads in flight (16 rows/wave).
__global__ __launch_bounds__(256) void agg_kernel(
    const float* __restrict__ edge_attr,
    const int* __restrict__ offs,
    const int* __restrict__ eids,
    float* __restrict__ agg)
{
    const int n = (blockIdx.x * 256 + threadIdx.x) >> 6;
    if (n >= N_NODES) return;
    const int lane = threadIdx.x & 63;
    const int q4 = (lane & 15) << 2;  // dim offset
    const int slot = lane >> 4;       // edge slot 0..3
    const int beg = (n == 0) ? 0 : offs[n - 1];
    const int deg = offs[n] - beg;

    float4 acc = make_float4(0.f, 0.f, 0.f, 0.f);
    int i = slot;
    for (; i + 12 < deg; i += 16) {
        const int e0 = eids[beg + i];
        const int e1 = eids[beg + i + 4];
        const int e2 = eids[beg + i + 8];
        const int e3 = eids[beg + i + 12];
        const float4 v0 = *reinterpret_cast<const float4*>(edge_attr + (size_t)e0 * DD + q4);
        const float4 v1 = *reinterpret_cast<const float4*>(edge_attr + (size_t)e1 * DD + q4);
        const float4 v2 = *reinterpret_cast<const float4*>(edge_attr + (size_t)e2 * DD + q4);
        const float4 v3 = *reinterpret_cast<const float4*>(edge_attr + (size_t)e3 * DD + q4);
        acc.x += v0.x + v1.x + v2.x + v3.x;
        acc.y += v0.y + v1.y + v2.y + v3.y;
        acc.z += v0.z + v1.z + v2.z + v3.z;
        acc.w += v0.w + v1.w + v2.w + v3.w;
    }
    for (; i < deg; i += 4) {
        const int e0 = eids[beg + i];
        const float4 v0 = *reinterpret_cast<const float4*>(edge_attr + (size_t)e0 * DD + q4);
        acc.x += v0.x; acc.y += v0.y; acc.z += v0.z; acc.w += v0.w;
    }
    #pragma unroll
    for (int m = 16; m < 64; m <<= 1) {
        acc.x += __shfl_xor(acc.x, m, 64);
        acc.y += __shfl_xor(acc.y, m, 64);
        acc.z += __shfl_xor(acc.z, m, 64);
        acc.w += __shfl_xor(acc.w, m, 64);
    }
    if (slot == 0)
        *reinterpret_cast<float4*>(agg + (size_t)n * DD + q4) = acc;
}

// ---------------- fused 2-layer MLP: 8 waves x 8 output dims ----------------
__global__ __launch_bounds__(512) void mlp_kernel(
    const float* __restrict__ x,
    const float* __restrict__ agg,
    const float* __restrict__ u,
    const int* __restrict__ batch,
    const float* __restrict__ W1,
    const float* __restrict__ b1,
    const float* __restrict__ W2,
    const float* __restrict__ b2,
    float* __restrict__ out)
{
    __shared__ float sh[64][65];
    const int lane = threadIdx.x & 63;
    const int j0 = __builtin_amdgcn_readfirstlane((threadIdx.x >> 6) << 3);
    const int node = blockIdx.x * 64 + lane;
    const bool valid = node < N_NODES;
    const int nc = valid ? node : (N_NODES - 1);

    float acc[8];
    #pragma unroll
    for (int j = 0; j < 8; ++j) acc[j] = b1[j0 + j];

    const float* __restrict__ row0 = x + (size_t)nc * DD;
    const float* __restrict__ row1 = agg + (size_t)nc * DD;
    const float* __restrict__ row2 = u + (size_t)batch[nc] * DD;

    #pragma unroll
    for (int s = 0; s < 3; ++s) {
        const float* __restrict__ row = (s == 0) ? row0 : (s == 1) ? row1 : row2;
        const float* __restrict__ w = W1 + (size_t)s * 64 * 64 + j0;
        for (int kk = 0; kk < 64; kk += 4) {
            const float4 v = *reinterpret_cast<const float4*>(row + kk);
            #pragma unroll
            for (int i = 0; i < 4; ++i) {
                const float iv = (i == 0) ? v.x : (i == 1) ? v.y : (i == 2) ? v.z : v.w;
                const float* __restrict__ wr = w + (size_t)(kk + i) * 64;
                #pragma unroll
                for (int j = 0; j < 8; ++j)
                    acc[j] += iv * wr[j];
            }
        }
    }

    #pragma unroll
    for (int j = 0; j < 8; ++j)
        sh[lane][j0 + j] = swish_f(acc[j]);

    __syncthreads();

    float acc2[8];
    #pragma unroll
    for (int j = 0; j < 8; ++j) acc2[j] = b2[j0 + j];
    for (int k = 0; k < 64; ++k) {
        const float hk = sh[lane][k];
        const float* __restrict__ wr = W2 + (size_t)k * 64 + j0;
        #pragma unroll
        for (int j = 0; j < 8; ++j)
            acc2[j] += hk * wr[j];
    }

    if (valid) {
        float* o = out + (size_t)node * DD + j0;
        #pragma unroll
        for (int j = 0; j < 8; j += 4) {
            float4 r;
            r.x = swish_f(acc2[j + 0]);
            r.y = swish_f(acc2[j + 1]);
            r.z = swish_f(acc2[j + 2]);
            r.w = swish_f(acc2[j + 3]);
            *reinterpret_cast<float4*>(o + j) = r;
        }
    }
}

extern "C" void kernel_launch(void* const* d_in, const int* in_sizes, int n_in,
                              void* d_out, int out_size, void* d_ws, size_t ws_size,
                              hipStream_t stream) {
    const float* x         = (const float*)d_in[0];
    const int*   ei        = (const int*)d_in[1];
    const float* edge_attr = (const float*)d_in[2];
    const float* u         = (const float*)d_in[3];
    const int*   batch     = (const int*)d_in[4];
    const float* W1        = (const float*)d_in[5];
    const float* b1        = (const float*)d_in[6];
    const float* W2        = (const float*)d_in[7];
    const float* b2        = (const float*)d_in[8];
    float* out = (float*)d_out;

    float* agg = (float*)d_ws;
    int* offs  = (int*)((char*)d_ws + (size_t)N_NODES * DD * sizeof(float));
    int* eids  = offs + N_NODES;
    int* bsum  = eids + N_EDGES;
    const int* col = ei + N_EDGES;   // edge_index[1]

    zero_kernel<<<(12500 + 255) / 256, 256, 0, stream>>>((int4*)offs, 12500);
    hist_kernel<<<(N_EDGES / 4 + 255) / 256, 256, 0, stream>>>(col, offs);
    scanA_kernel<<<SCAN_BLOCKS, 256, 0, stream>>>(offs, bsum);
    scanB_kernel<<<1, 256, 0, stream>>>(bsum);
    scanC_kernel<<<SCAN_BLOCKS, 256, 0, stream>>>(offs, bsum);
    fill_kernel<<<(N_EDGES / 4 + 255) / 256, 256, 0, stream>>>(col, offs, eids);
    agg_kernel<<<(N_NODES + 3) / 4, 256, 0, stream>>>(edge_attr, offs, eids, agg);
    mlp_kernel<<<(N_NODES + 63) / 64, 512, 0, stream>>>(x, agg, u, batch, W1, b1, W2, b2, out);
}

// Round 8
// 182.357 us; speedup vs baseline: 1.4482x; 1.0035x over previous
//
#include <hip/hip_runtime.h>
#include <hip/hip_bf16.h>

#define N_NODES 50000
#define N_EDGES 800000
#define DD 64
#define NGRAPH 64
#define SCAN_BLOCKS ((N_NODES + 255) / 256)   // 196

// R1/R3: 51.2M f32 atomics = 682us (op-rate-bound) -> CSR+gather.
// R7: coalesced 3-phase scan + unroll4 gather -> 183us (prediction hit).
// R8: fuse agg+mlp (agg rows live only in LDS; saves 25.6MB + hides MLP),
// merge scanB+scanC. 8 -> 6 dispatches.
//
// ws layout: offs[50000] i32 | eids[800000] i32 | bsum[256] i32  (~3.4 MB)

__device__ __forceinline__ float swish_f(float v) {
    return v / (1.0f + __expf(-v));
}

__global__ __launch_bounds__(256) void zero_kernel(int4* __restrict__ p, int n4)
{
    const int i = blockIdx.x * 256 + threadIdx.x;
    if (i < n4) p[i] = make_int4(0, 0, 0, 0);
}

// 4 edges per thread via int4 (N_EDGES % 4 == 0)
__global__ __launch_bounds__(256) void hist_kernel(
    const int* __restrict__ col, int* __restrict__ cnt)
{
    const int i = blockIdx.x * 256 + threadIdx.x;
    if (i < N_EDGES / 4) {
        const int4 c = reinterpret_cast<const int4*>(col)[i];
        atomicAdd(&cnt[c.x], 1);
        atomicAdd(&cnt[c.y], 1);
        atomicAdd(&cnt[c.z], 1);
        atomicAdd(&cnt[c.w], 1);
    }
}

// A: per-block scan -> offs[idx] = exclusive-within-block; bsum[b] = block total
__global__ __launch_bounds__(256) void scanA_kernel(
    int* __restrict__ offs, int* __restrict__ bsum)
{
    __shared__ int sm[256];
    const int t = threadIdx.x;
    const int idx = blockIdx.x * 256 + t;
    const int v = (idx < N_NODES) ? offs[idx] : 0;
    sm[t] = v;
    __syncthreads();
    #pragma unroll
    for (int d = 1; d < 256; d <<= 1) {
        const int w = (t >= d) ? sm[t - d] : 0;
        __syncthreads();
        sm[t] += w;
        __syncthreads();
    }
    if (idx < N_NODES) offs[idx] = sm[t] - v;
    if (t == 255) bsum[blockIdx.x] = sm[255];
}

// B+C merged: every block redundantly scans bsum in LDS, adds its own base.
__global__ __launch_bounds__(256) void scanBC_kernel(
    int* __restrict__ offs, const int* __restrict__ bsum)
{
    __shared__ int sm[256];
    __shared__ int base;
    const int t = threadIdx.x;
    sm[t] = (t < SCAN_BLOCKS) ? bsum[t] : 0;
    __syncthreads();
    #pragma unroll
    for (int d = 1; d < 256; d <<= 1) {
        const int w = (t >= d) ? sm[t - d] : 0;
        __syncthreads();
        sm[t] += w;
        __syncthreads();
    }
    if (t == 0) base = (blockIdx.x == 0) ? 0 : sm[blockIdx.x - 1];
    __syncthreads();
    const int idx = blockIdx.x * 256 + t;
    if (idx < N_NODES) offs[idx] += base;
}

// offs[n] = start(n) on entry; on exit offs[n] = start(n+1) (mutated by atomics).
__global__ __launch_bounds__(256) void fill_kernel(
    const int* __restrict__ col, int* __restrict__ offs, int* __restrict__ eids)
{
    const int i = blockIdx.x * 256 + threadIdx.x;
    if (i < N_EDGES / 4) {
        const int4 c = reinterpret_cast<const int4*>(col)[i];
        const int e = i * 4;
        eids[atomicAdd(&offs[c.x], 1)] = e + 0;
        eids[atomicAdd(&offs[c.y], 1)] = e + 1;
        eids[atomicAdd(&offs[c.z], 1)] = e + 2;
        eids[atomicAdd(&offs[c.w], 1)] = e + 3;
    }
}

// ---- fused aggregate + 2-layer MLP ----
// 512 threads (8 waves) per block own 64 nodes.
// Phase A: wave w aggregates nodes w*8..w*8+7 (16 dim-lanes x 4 edge slots,
//          unroll x4) into LDS sh[node][dim], stride 65 -> 2-way banks (free).
// Phase B: thread (wave w, lane l) computes dims [w*8, w*8+8) of node l.
__global__ __launch_bounds__(512) void agg_mlp_kernel(
    const float* __restrict__ edge_attr,
    const int* __restrict__ offs,
    const int* __restrict__ eids,
    const float* __restrict__ x,
    const float* __restrict__ u,
    const int* __restrict__ batch,
    const float* __restrict__ W1,
    const float* __restrict__ b1,
    const float* __restrict__ W2,
    const float* __restrict__ b2,
    float* __restrict__ out)
{
    __shared__ float sh[64][65];
    const int t = threadIdx.x;
    const int lane = t & 63;
    const int w = t >> 6;               // wave 0..7
    const int q4 = (lane & 15) << 2;    // dim offset 0,4,...,60
    const int slot = lane >> 4;         // edge slot 0..3

    // ---------- phase A: aggregate ----------
    #pragma unroll
    for (int i = 0; i < 8; ++i) {
        const int nl = w * 8 + i;
        const int n = blockIdx.x * 64 + nl;
        float4 acc = make_float4(0.f, 0.f, 0.f, 0.f);
        if (n < N_NODES) {
            const int beg = (n == 0) ? 0 : offs[n - 1];
            const int deg = offs[n] - beg;
            int ii = slot;
            for (; ii + 12 < deg; ii += 16) {
                const int e0 = eids[beg + ii];
                const int e1 = eids[beg + ii + 4];
                const int e2 = eids[beg + ii + 8];
                const int e3 = eids[beg + ii + 12];
                const float4 v0 = *reinterpret_cast<const float4*>(edge_attr + (size_t)e0 * DD + q4);
                const float4 v1 = *reinterpret_cast<const float4*>(edge_attr + (size_t)e1 * DD + q4);
                const float4 v2 = *reinterpret_cast<const float4*>(edge_attr + (size_t)e2 * DD + q4);
                const float4 v3 = *reinterpret_cast<const float4*>(edge_attr + (size_t)e3 * DD + q4);
                acc.x += v0.x + v1.x + v2.x + v3.x;
                acc.y += v0.y + v1.y + v2.y + v3.y;
                acc.z += v0.z + v1.z + v2.z + v3.z;
                acc.w += v0.w + v1.w + v2.w + v3.w;
            }
            for (; ii < deg; ii += 4) {
                const int e0 = eids[beg + ii];
                const float4 v0 = *reinterpret_cast<const float4*>(edge_attr + (size_t)e0 * DD + q4);
                acc.x += v0.x; acc.y += v0.y; acc.z += v0.z; acc.w += v0.w;
            }
        }
        #pragma unroll
        for (int m = 16; m < 64; m <<= 1) {
            acc.x += __shfl_xor(acc.x, m, 64);
            acc.y += __shfl_xor(acc.y, m, 64);
            acc.z += __shfl_xor(acc.z, m, 64);
            acc.w += __shfl_xor(acc.w, m, 64);
        }
        if (slot == 0) {
            sh[nl][q4 + 0] = acc.x;
            sh[nl][q4 + 1] = acc.y;
            sh[nl][q4 + 2] = acc.z;
            sh[nl][q4 + 3] = acc.w;
        }
    }
    __syncthreads();

    // ---------- phase B: MLP ----------
    const int j0 = __builtin_amdgcn_readfirstlane(w << 3);
    const int node = blockIdx.x * 64 + lane;
    const bool valid = node < N_NODES;
    const int nc = valid ? node : (N_NODES - 1);

    float acc[8];
    #pragma unroll
    for (int j = 0; j < 8; ++j) acc[j] = b1[j0 + j];

    // segment 0: x (global, float4)
    {
        const float* __restrict__ row = x + (size_t)nc * DD;
        const float* __restrict__ wp = W1 + j0;
        for (int kk = 0; kk < 64; kk += 4) {
            const float4 v = *reinterpret_cast<const float4*>(row + kk);
            #pragma unroll
            for (int i = 0; i < 4; ++i) {
                const float iv = (i == 0) ? v.x : (i == 1) ? v.y : (i == 2) ? v.z : v.w;
                const float* __restrict__ wr = wp + (size_t)(kk + i) * 64;
                #pragma unroll
                for (int j = 0; j < 8; ++j) acc[j] += iv * wr[j];
            }
        }
    }
    // segment 1: aggregated (LDS row `lane`)
    {
        const float* __restrict__ wp = W1 + (size_t)64 * 64 + j0;
        for (int k = 0; k < 64; ++k) {
            const float iv = sh[lane][k];
            const float* __restrict__ wr = wp + (size_t)k * 64;
            #pragma unroll
            for (int j = 0; j < 8; ++j) acc[j] += iv * wr[j];
        }
    }
    // segment 2: u[batch] (global, float4)
    {
        const float* __restrict__ row = u + (size_t)batch[nc] * DD;
        const float* __restrict__ wp = W1 + (size_t)128 * 64 + j0;
        for (int kk = 0; kk < 64; kk += 4) {
            const float4 v = *reinterpret_cast<const float4*>(row + kk);
            #pragma unroll
            for (int i = 0; i < 4; ++i) {
                const float iv = (i == 0) ? v.x : (i == 1) ? v.y : (i == 2) ? v.z : v.w;
                const float* __restrict__ wr = wp + (size_t)(kk + i) * 64;
                #pragma unroll
                for (int j = 0; j < 8; ++j) acc[j] += iv * wr[j];
            }
        }
    }

    __syncthreads();   // all LDS agg reads complete before overwrite with h
    #pragma unroll
    for (int j = 0; j < 8; ++j)
        sh[lane][j0 + j] = swish_f(acc[j]);
    __syncthreads();

    float acc2[8];
    #pragma unroll
    for (int j = 0; j < 8; ++j) acc2[j] = b2[j0 + j];
    for (int k = 0; k < 64; ++k) {
        const float hk = sh[lane][k];
        const float* __restrict__ wr = W2 + (size_t)k * 64 + j0;
        #pragma unroll
        for (int j = 0; j < 8; ++j) acc2[j] += hk * wr[j];
    }

    if (valid) {
        float* o = out + (size_t)node * DD + j0;
        #pragma unroll
        for (int j = 0; j < 8; j += 4) {
            float4 r;
            r.x = swish_f(acc2[j + 0]);
            r.y = swish_f(acc2[j + 1]);
            r.z = swish_f(acc2[j + 2]);
            r.w = swish_f(acc2[j + 3]);
            *reinterpret_cast<float4*>(o + j) = r;
        }
    }
}

extern "C" void kernel_launch(void* const* d_in, const int* in_sizes, int n_in,
                              void* d_out, int out_size, void* d_ws, size_t ws_size,
                              hipStream_t stream) {
    const float* x         = (const float*)d_in[0];
    const int*   ei        = (const int*)d_in[1];
    const float* edge_attr = (const float*)d_in[2];
    const float* u         = (const float*)d_in[3];
    const int*   batch     = (const int*)d_in[4];
    const float* W1        = (const float*)d_in[5];
    const float* b1        = (const float*)d_in[6];
    const float* W2        = (const float*)d_in[7];
    const float* b2        = (const float*)d_in[8];
    float* out = (float*)d_out;

    int* offs = (int*)d_ws;
    int* eids = offs + N_NODES;
    int* bsum = eids + N_EDGES;
    const int* col = ei + N_EDGES;   // edge_index[1]

    zero_kernel<<<(12500 + 255) / 256, 256, 0, stream>>>((int4*)offs, 12500);
    hist_kernel<<<(N_EDGES / 4 + 255) / 256, 256, 0, stream>>>(col, offs);
    scanA_kernel<<<SCAN_BLOCKS, 256, 0, stream>>>(offs, bsum);
    scanBC_kernel<<<SCAN_BLOCKS, 256, 0, stream>>>(offs, bsum);
    fill_kernel<<<(N_EDGES / 4 + 255) / 256, 256, 0, stream>>>(col, offs, eids);
    agg_mlp_kernel<<<(N_NODES + 63) / 64, 512, 0, stream>>>(
        edge_attr, offs, eids, x, u, batch, W1, b1, W2, b2, out);
}

// Round 9
// 178.270 us; speedup vs baseline: 1.4814x; 1.0229x over previous
//
#include <hip/hip_runtime.h>
#include <hip/hip_bf16.h>

#define N_NODES 50000
#define N_EDGES 800000
#define DD 64
#define NGRAPH 64
#define SCAN_BLOCKS ((N_NODES + 255) / 256)   // 196

// R1/R3: 51.2M f32 atomics = 682us (op-rate-bound) -> CSR+gather.
// R7: coalesced scan + gather ILP -> 183us. R8: fused agg+mlp neutral (182us)
// but measured: gather 813 GB/s, VALU 13% -> latency-bound. Root cause: R6's
// strided slot split made slots 1-3 run a 1-deep divergent remainder for
// deg~16. R9: branch-free gather (contiguous per-slot quarters, uniform trip
// count, clamp+mask tail), un-fused agg/mlp (fusion was neutral, costs waves).
//
// ws layout: agg[50000*64] f32 | offs[50000] i32 | eids[800000] i32 | bsum[256]

__device__ __forceinline__ float swish_f(float v) {
    return v / (1.0f + __expf(-v));
}

__global__ __launch_bounds__(256) void zero_kernel(int4* __restrict__ p, int n4)
{
    const int i = blockIdx.x * 256 + threadIdx.x;
    if (i < n4) p[i] = make_int4(0, 0, 0, 0);
}

// 4 edges per thread via int4 (N_EDGES % 4 == 0)
__global__ __launch_bounds__(256) void hist_kernel(
    const int* __restrict__ col, int* __restrict__ cnt)
{
    const int i = blockIdx.x * 256 + threadIdx.x;
    if (i < N_EDGES / 4) {
        const int4 c = reinterpret_cast<const int4*>(col)[i];
        atomicAdd(&cnt[c.x], 1);
        atomicAdd(&cnt[c.y], 1);
        atomicAdd(&cnt[c.z], 1);
        atomicAdd(&cnt[c.w], 1);
    }
}

// A: per-block scan -> offs[idx] = exclusive-within-block; bsum[b] = block total
__global__ __launch_bounds__(256) void scanA_kernel(
    int* __restrict__ offs, int* __restrict__ bsum)
{
    __shared__ int sm[256];
    const int t = threadIdx.x;
    const int idx = blockIdx.x * 256 + t;
    const int v = (idx < N_NODES) ? offs[idx] : 0;
    sm[t] = v;
    __syncthreads();
    #pragma unroll
    for (int d = 1; d < 256; d <<= 1) {
        const int w = (t >= d) ? sm[t - d] : 0;
        __syncthreads();
        sm[t] += w;
        __syncthreads();
    }
    if (idx < N_NODES) offs[idx] = sm[t] - v;
    if (t == 255) bsum[blockIdx.x] = sm[255];
}

// B+C merged: every block redundantly scans bsum in LDS, adds its own base.
__global__ __launch_bounds__(256) void scanBC_kernel(
    int* __restrict__ offs, const int* __restrict__ bsum)
{
    __shared__ int sm[256];
    __shared__ int base;
    const int t = threadIdx.x;
    sm[t] = (t < SCAN_BLOCKS) ? bsum[t] : 0;
    __syncthreads();
    #pragma unroll
    for (int d = 1; d < 256; d <<= 1) {
        const int w = (t >= d) ? sm[t - d] : 0;
        __syncthreads();
        sm[t] += w;
        __syncthreads();
    }
    if (t == 0) base = (blockIdx.x == 0) ? 0 : sm[blockIdx.x - 1];
    __syncthreads();
    const int idx = blockIdx.x * 256 + t;
    if (idx < N_NODES) offs[idx] += base;
}

// offs[n] = start(n) on entry; on exit offs[n] = start(n+1) (mutated by atomics).
__global__ __launch_bounds__(256) void fill_kernel(
    const int* __restrict__ col, int* __restrict__ offs, int* __restrict__ eids)
{
    const int i = blockIdx.x * 256 + threadIdx.x;
    if (i < N_EDGES / 4) {
        const int4 c = reinterpret_cast<const int4*>(col)[i];
        const int e = i * 4;
        eids[atomicAdd(&offs[c.x], 1)] = e + 0;
        eids[atomicAdd(&offs[c.y], 1)] = e + 1;
        eids[atomicAdd(&offs[c.z], 1)] = e + 2;
        eids[atomicAdd(&offs[c.w], 1)] = e + 3;
    }
}

// one wave per node: 16 dim-lanes x float4; slot s owns a CONTIGUOUS quarter
// of the node's edge list; trip count wave-uniform (deg is wave-uniform);
// tail via index-clamp + 0-mask -> branch-free, 4 eid + 4 row loads always
// in flight per slot. (R8 lesson: divergent remainder ran the gather 1-deep.)
__global__ __launch_bounds__(256) void agg_kernel(
    const float* __restrict__ edge_attr,
    const int* __restrict__ offs,
    const int* __restrict__ eids,
    float* __restrict__ agg)
{
    const int n = (blockIdx.x * 256 + threadIdx.x) >> 6;
    if (n >= N_NODES) return;
    const int lane = threadIdx.x & 63;
    const int q4 = (lane & 15) << 2;  // dim offset
    const int slot = lane >> 4;       // edge-quarter 0..3
    const int beg = (n == 0) ? 0 : offs[n - 1];
    const int deg = offs[n] - beg;

    float4 acc = make_float4(0.f, 0.f, 0.f, 0.f);
    if (deg > 0) {                                   // wave-uniform branch
        const int qcnt  = (deg + 3) >> 2;            // per-slot quota
        const int s_beg = beg + slot * qcnt;
        const int s_end = min(beg + deg, s_beg + qcnt);
        const int last  = beg + deg - 1;
        const int s_lim = s_beg + qcnt;              // uniform loop bound
        for (int i = s_beg; i < s_lim; i += 4) {
            const int i0 = min(i + 0, last);
            const int i1 = min(i + 1, last);
            const int i2 = min(i + 2, last);
            const int i3 = min(i + 3, last);
            const float m0 = (i + 0 < s_end) ? 1.f : 0.f;
            const float m1 = (i + 1 < s_end) ? 1.f : 0.f;
            const float m2 = (i + 2 < s_end) ? 1.f : 0.f;
            const float m3 = (i + 3 < s_end) ? 1.f : 0.f;
            const int e0 = eids[i0];
            const int e1 = eids[i1];
            const int e2 = eids[i2];
            const int e3 = eids[i3];
            const float4 v0 = *reinterpret_cast<const float4*>(edge_attr + (size_t)e0 * DD + q4);
            const float4 v1 = *reinterpret_cast<const float4*>(edge_attr + (size_t)e1 * DD + q4);
            const float4 v2 = *reinterpret_cast<const float4*>(edge_attr + (size_t)e2 * DD + q4);
            const float4 v3 = *reinterpret_cast<const float4*>(edge_attr + (size_t)e3 * DD + q4);
            acc.x += m0 * v0.x + m1 * v1.x + m2 * v2.x + m3 * v3.x;
            acc.y += m0 * v0.y + m1 * v1.y + m2 * v2.y + m3 * v3.y;
            acc.z += m0 * v0.z + m1 * v1.z + m2 * v2.z + m3 * v3.z;
            acc.w += m0 * v0.w + m1 * v1.w + m2 * v2.w + m3 * v3.w;
        }
    }
    #pragma unroll
    for (int m = 16; m < 64; m <<= 1) {
        acc.x += __shfl_xor(acc.x, m, 64);
        acc.y += __shfl_xor(acc.y, m, 64);
        acc.z += __shfl_xor(acc.z, m, 64);
        acc.w += __shfl_xor(acc.w, m, 64);
    }
    if (slot == 0)
        *reinterpret_cast<float4*>(agg + (size_t)n * DD + q4) = acc;
}

// ---------------- fused 2-layer MLP: 8 waves x 8 output dims ----------------
__global__ __launch_bounds__(512) void mlp_kernel(
    const float* __restrict__ x,
    const float* __restrict__ agg,
    const float* __restrict__ u,
    const int* __restrict__ batch,
    const float* __restrict__ W1,
    const float* __restrict__ b1,
    const float* __restrict__ W2,
    const float* __restrict__ b2,
    float* __restrict__ out)
{
    __shared__ float sh[64][65];
    const int lane = threadIdx.x & 63;
    const int j0 = __builtin_amdgcn_readfirstlane((threadIdx.x >> 6) << 3);
    const int node = blockIdx.x * 64 + lane;
    const bool valid = node < N_NODES;
    const int nc = valid ? node : (N_NODES - 1);

    float acc[8];
    #pragma unroll
    for (int j = 0; j < 8; ++j) acc[j] = b1[j0 + j];

    const float* __restrict__ row0 = x + (size_t)nc * DD;
    const float* __restrict__ row1 = agg + (size_t)nc * DD;
    const float* __restrict__ row2 = u + (size_t)batch[nc] * DD;

    #pragma unroll
    for (int s = 0; s < 3; ++s) {
        const float* __restrict__ row = (s == 0) ? row0 : (s == 1) ? row1 : row2;
        const float* __restrict__ w = W1 + (size_t)s * 64 * 64 + j0;
        for (int kk = 0; kk < 64; kk += 4) {
            const float4 v = *reinterpret_cast<const float4*>(row + kk);
            #pragma unroll
            for (int i = 0; i < 4; ++i) {
                const float iv = (i == 0) ? v.x : (i == 1) ? v.y : (i == 2) ? v.z : v.w;
                const float* __restrict__ wr = w + (size_t)(kk + i) * 64;
                #pragma unroll
                for (int j = 0; j < 8; ++j)
                    acc[j] += iv * wr[j];
            }
        }
    }

    #pragma unroll
    for (int j = 0; j < 8; ++j)
        sh[lane][j0 + j] = swish_f(acc[j]);

    __syncthreads();

    float acc2[8];
    #pragma unroll
    for (int j = 0; j < 8; ++j) acc2[j] = b2[j0 + j];
    for (int k = 0; k < 64; ++k) {
        const float hk = sh[lane][k];
        const float* __restrict__ wr = W2 + (size_t)k * 64 + j0;
        #pragma unroll
        for (int j = 0; j < 8; ++j)
            acc2[j] += hk * wr[j];
    }

    if (valid) {
        float* o = out + (size_t)node * DD + j0;
        #pragma unroll
        for (int j = 0; j < 8; j += 4) {
            float4 r;
            r.x = swish_f(acc2[j + 0]);
            r.y = swish_f(acc2[j + 1]);
            r.z = swish_f(acc2[j + 2]);
            r.w = swish_f(acc2[j + 3]);
            *reinterpret_cast<float4*>(o + j) = r;
        }
    }
}

extern "C" void kernel_launch(void* const* d_in, const int* in_sizes, int n_in,
                              void* d_out, int out_size, void* d_ws, size_t ws_size,
                              hipStream_t stream) {
    const float* x         = (const float*)d_in[0];
    const int*   ei        = (const int*)d_in[1];
    const float* edge_attr = (const float*)d_in[2];
    const float* u         = (const float*)d_in[3];
    const int*   batch     = (const int*)d_in[4];
    const float* W1        = (const float*)d_in[5];
    const float* b1        = (const float*)d_in[6];
    const float* W2        = (const float*)d_in[7];
    const float* b2        = (const float*)d_in[8];
    float* out = (float*)d_out;

    float* agg = (float*)d_ws;
    int* offs  = (int*)((char*)d_ws + (size_t)N_NODES * DD * sizeof(float));
    int* eids  = offs + N_NODES;
    int* bsum  = eids + N_EDGES;
    const int* col = ei + N_EDGES;   // edge_index[1]

    zero_kernel<<<(12500 + 255) / 256, 256, 0, stream>>>((int4*)offs, 12500);
    hist_kernel<<<(N_EDGES / 4 + 255) / 256, 256, 0, stream>>>(col, offs);
    scanA_kernel<<<SCAN_BLOCKS, 256, 0, stream>>>(offs, bsum);
    scanBC_kernel<<<SCAN_BLOCKS, 256, 0, stream>>>(offs, bsum);
    fill_kernel<<<(N_EDGES / 4 + 255) / 256, 256, 0, stream>>>(col, offs, eids);
    agg_kernel<<<(N_NODES + 3) / 4, 256, 0, stream>>>(edge_attr, offs, eids, agg);
    mlp_kernel<<<(N_NODES + 63) / 64, 512, 0, stream>>>(x, agg, u, batch, W1, b1, W2, b2, out);
}